// Round 1
// baseline (1340.731 us; speedup 1.0000x reference)
//
#include <hip/hip_runtime.h>

#define N_NODES 16000
#define DIM 128
#define CHUNK 32

// ---------------------------------------------------------------------------
// K1: colsum[k] = sum_i h[i][k].  128 blocks x 125 rows each, 128 threads
// (one per column, coalesced), per-block sequential partial sum then one
// atomicAdd per column per block.
// ---------------------------------------------------------------------------
__global__ __launch_bounds__(128) void colsum_kernel(const float* __restrict__ h,
                                                     float* __restrict__ colsum) {
    const int t = threadIdx.x;          // column 0..127
    const int r0 = blockIdx.x * 125;    // 128 * 125 = 16000 rows
    float acc = 0.f;
    for (int r = r0; r < r0 + 125; ++r) acc += h[r * DIM + t];
    atomicAdd(&colsum[t], acc);
}

// ---------------------------------------------------------------------------
// K2: stream g (1.024 GB) as float4; for the (rare) entries with !(g>0),
// accumulate h[src] into corr[dst].  agg[j] = colsum - corr[j].
// ---------------------------------------------------------------------------
__global__ __launch_bounds__(256) void scan_kernel(const float* __restrict__ g,
                                                   const float* __restrict__ h,
                                                   float* __restrict__ corr) {
    const int total4 = (N_NODES * N_NODES) / 4;   // 64,000,000 (fits int32)
    const int stride = gridDim.x * blockDim.x;
    const float4* g4 = (const float4*)g;
    for (int p = blockIdx.x * blockDim.x + threadIdx.x; p < total4; p += stride) {
        const float4 v = g4[p];
        if (v.x > 0.f && v.y > 0.f && v.z > 0.f && v.w > 0.f) continue;
        // rare path: identify which lanes are non-positive
        const float vals[4] = {v.x, v.y, v.z, v.w};
        const int base = p * 4;
#pragma unroll
        for (int l = 0; l < 4; ++l) {
            if (!(vals[l] > 0.f)) {
                const int q = base + l;              // flat index into g[i][j]
                const int i = q / N_NODES;           // src row
                const int j = q - i * N_NODES;       // dst col
                const float* hs = &h[i * DIM];
                float* cj = &corr[j * DIM];
                for (int k = 0; k < DIM; ++k) atomicAdd(&cj[k], hs[k]);
            }
        }
    }
}

// ---------------------------------------------------------------------------
// K3: one dense layer  Y = relu(X' @ W + b), where X' = X + colsum - corr
// when add_agg != 0, else X' = X.  Thread t holds W column t in 128 VGPRs;
// activations staged in LDS and read as broadcast float4.  Safe to run
// in-place (X == Y): each block stages its own rows into LDS before writing.
// ---------------------------------------------------------------------------
__global__ __launch_bounds__(128, 2) void mlp_kernel(const float* X,
                                                     const float* __restrict__ corr,
                                                     const float* __restrict__ colsum,
                                                     const float* __restrict__ W,
                                                     const float* __restrict__ bias,
                                                     float* Y, int add_agg) {
    __shared__ float ys[CHUNK][DIM];
    const int t = threadIdx.x;                 // output column 0..127
    const int node0 = blockIdx.x * CHUNK;

    float w[DIM];
#pragma unroll
    for (int d = 0; d < DIM; ++d) w[d] = W[d * DIM + t];
    const float bk = bias[t];
    const float cs = add_agg ? colsum[t] : 0.f;

    for (int n = 0; n < CHUNK; ++n) {
        const int node = node0 + n;
        float v = X[node * DIM + t];
        if (add_agg) v += cs - corr[node * DIM + t];
        ys[n][t] = v;
    }
    __syncthreads();

    for (int n0 = 0; n0 < CHUNK; n0 += 4) {
        float a0 = bk, a1 = bk, a2 = bk, a3 = bk;
#pragma unroll
        for (int d = 0; d < DIM; d += 4) {
            const float4 y0 = *(const float4*)&ys[n0 + 0][d];
            const float4 y1 = *(const float4*)&ys[n0 + 1][d];
            const float4 y2 = *(const float4*)&ys[n0 + 2][d];
            const float4 y3 = *(const float4*)&ys[n0 + 3][d];
            a0 += y0.x * w[d] + y0.y * w[d + 1] + y0.z * w[d + 2] + y0.w * w[d + 3];
            a1 += y1.x * w[d] + y1.y * w[d + 1] + y1.z * w[d + 2] + y1.w * w[d + 3];
            a2 += y2.x * w[d] + y2.y * w[d + 1] + y2.z * w[d + 2] + y2.w * w[d + 3];
            a3 += y3.x * w[d] + y3.y * w[d + 1] + y3.z * w[d + 2] + y3.w * w[d + 3];
        }
        Y[(node0 + n0 + 0) * DIM + t] = fmaxf(a0, 0.f);
        Y[(node0 + n0 + 1) * DIM + t] = fmaxf(a1, 0.f);
        Y[(node0 + n0 + 2) * DIM + t] = fmaxf(a2, 0.f);
        Y[(node0 + n0 + 3) * DIM + t] = fmaxf(a3, 0.f);
    }
}

extern "C" void kernel_launch(void* const* d_in, const int* in_sizes, int n_in,
                              void* d_out, int out_size, void* d_ws, size_t ws_size,
                              hipStream_t stream) {
    const float* g  = (const float*)d_in[0];   // [16000, 16000]
    const float* h  = (const float*)d_in[1];   // [16000, 128]
    const float* W1 = (const float*)d_in[2];   // [128, 128]
    const float* b1 = (const float*)d_in[3];   // [128]
    const float* W2 = (const float*)d_in[4];   // [128, 128]
    const float* b2 = (const float*)d_in[5];   // [128]
    float* out = (float*)d_out;                // [16000, 128]

    // ws layout: corr [16000*128] fp32, then colsum [128] fp32
    float* corr   = (float*)d_ws;
    float* colsum = corr + (size_t)N_NODES * DIM;

    hipMemsetAsync(d_ws, 0, ((size_t)N_NODES * DIM + DIM) * sizeof(float), stream);

    colsum_kernel<<<128, 128, 0, stream>>>(h, colsum);
    scan_kernel<<<16384, 256, 0, stream>>>(g, h, corr);

    // layer 1: out = relu((h + colsum - corr) @ W1 + b1)
    mlp_kernel<<<N_NODES / CHUNK, 128, 0, stream>>>(h, corr, colsum, W1, b1, out, 1);
    // layer 2 (in-place): out = relu(out @ W2 + b2)
    mlp_kernel<<<N_NODES / CHUNK, 128, 0, stream>>>(out, nullptr, nullptr, W2, b2, out, 0);
}